// Round 1
// baseline (72.876 us; speedup 1.0000x reference)
//
#include <hip/hip_runtime.h>

// GMP forward: out[b,j] = sum_i xc[j+i-7] * ( W0[i] + sum_m a*(w1 + a*(w2 + a*w3)) ),
// a = |xc[j+i+m-14]|.  B=64, T=16384, M=8, K=3. Weights real.
//
// R1 change vs previous best: the i-loop is ROLLED (#pragma unroll 1).
// The fully-unrolled version exposes all 200 weight loads + 40 LDS reads to the
// scheduler at once -> suspected VGPR blowup/scratch spill (kernel ~9x above its
// 2.8us VALU floor). Rolled: only 25 weights + 11-float amp window live per
// iteration (~70 VGPR). Windows are re-read from LDS with a runtime base and
// compile-time offsets (no runtime-indexed register arrays -> no scratch).
// VALU per output stays at the 208-FMA algebraic minimum.

#define B_SZ 64
#define T_SZ 16384
#define CHUNK 1024
#define HALO 14               // 2*(M-1)
#define WIN (CHUNK + HALO)    // 1038

__global__ __launch_bounds__(256, 4) void gmp_kernel(const float* __restrict__ x,
                                                     const float* __restrict__ W,
                                                     float* __restrict__ out) {
    __shared__ float2 xs[WIN];   // xc window
    __shared__ float  as[WIN];   // |xc| window
    const int tid   = threadIdx.x;
    const int chunk = blockIdx.x & 15;   // T/CHUNK = 16 chunks per row
    const int b     = blockIdx.x >> 4;
    const int j0    = chunk * CHUNK;

    // Stage window [j0-14, j0+1024) of row b; zero-pad g<0.
    for (int q = tid; q < WIN; q += 256) {
        const int g = j0 - HALO + q;
        float2 v = make_float2(0.f, 0.f);
        if (g >= 0) v = ((const float2*)x)[(size_t)b * T_SZ + g];
        xs[q] = v;
        as[q] = sqrtf(fmaf(v.x, v.x, v.y * v.y));
    }
    __syncthreads();

    // Each thread: outputs j = j0 + 4*tid + {0,1,2,3}.
    const int t4 = 4 * tid;

    float ar0 = 0.f, ar1 = 0.f, ar2 = 0.f, ar3 = 0.f;
    float ai0 = 0.f, ai1 = 0.f, ai2 = 0.f, ai3 = 0.f;

#pragma unroll 1
    for (int i = 0; i < 8; ++i) {
        const float*  __restrict__ ap = &as[t4 + i];       // amp window a[m+r], m+r in 0..10
        const float2* __restrict__ xp = &xs[t4 + 7 + i];   // x window, r in 0..3
        const float*  __restrict__ wp = &W[i * 25];        // this tap's 25 weights (uniform)

        const float w0 = wp[0];
        float c0 = w0, c1 = w0, c2 = w0, c3 = w0;

#pragma unroll
        for (int m = 0; m < 8; ++m) {
            const float w1 = wp[1 + 3 * m];
            const float w2 = wp[2 + 3 * m];
            const float w3 = wp[3 + 3 * m];
            {
                const float a = ap[m];
                float h = fmaf(a, w3, w2);
                h = fmaf(a, h, w1);
                c0 = fmaf(a, h, c0);
            }
            {
                const float a = ap[m + 1];
                float h = fmaf(a, w3, w2);
                h = fmaf(a, h, w1);
                c1 = fmaf(a, h, c1);
            }
            {
                const float a = ap[m + 2];
                float h = fmaf(a, w3, w2);
                h = fmaf(a, h, w1);
                c2 = fmaf(a, h, c2);
            }
            {
                const float a = ap[m + 3];
                float h = fmaf(a, w3, w2);
                h = fmaf(a, h, w1);
                c3 = fmaf(a, h, c3);
            }
        }

        const float2 x0 = xp[0];
        const float2 x1 = xp[1];
        const float2 x2 = xp[2];
        const float2 x3 = xp[3];
        ar0 = fmaf(x0.x, c0, ar0); ai0 = fmaf(x0.y, c0, ai0);
        ar1 = fmaf(x1.x, c1, ar1); ai1 = fmaf(x1.y, c1, ai1);
        ar2 = fmaf(x2.x, c2, ar2); ai2 = fmaf(x2.y, c2, ai2);
        ar3 = fmaf(x3.x, c3, ar3); ai3 = fmaf(x3.y, c3, ai3);
    }

    // Four consecutive complex outputs -> two 16B stores.
    float4* op = (float4*)&out[2 * ((size_t)b * T_SZ + j0 + t4)];
    op[0] = make_float4(ar0, ai0, ar1, ai1);
    op[1] = make_float4(ar2, ai2, ar3, ai3);
}

extern "C" void kernel_launch(void* const* d_in, const int* in_sizes, int n_in,
                              void* d_out, int out_size, void* d_ws, size_t ws_size,
                              hipStream_t stream) {
    const float* x = (const float*)d_in[0];
    // d_in[1] is h_0 (unused)
    const float* W = (const float*)d_in[2];
    float* out = (float*)d_out;
    const int grid = B_SZ * (T_SZ / CHUNK);  // 1024 blocks
    gmp_kernel<<<dim3(grid), dim3(256), 0, stream>>>(x, W, out);
}

// Round 2
// 69.844 us; speedup vs baseline: 1.0434x; 1.0434x over previous
//
#include <hip/hip_runtime.h>

// GMP forward: out[b,j] = sum_i xc[j+i-7] * ( W0[i] + sum_m a*(w1 + a*(w2 + a*w3)) ),
// a = |xc[j+i+m-14]|.  B=64, T=16384, M=8, K=3. Weights real.
//
// R2: rolled i-loop (small live set, ~70 VGPR, no spill) + SLIDING REGISTER
// WINDOW for a[] and x[] (no per-iteration LDS re-reads -> kills R1's 8-way
// bank-conflicted ds_read_b32 storm; only 2 ds refills per iteration).
// All register-array indices are compile-time (named scalars), so no scratch.
// VALU per output stays at the 208-FMA algebraic minimum (+ ~16 movs/iter).

#define B_SZ 64
#define T_SZ 16384
#define CHUNK 1024
#define HALO 14               // 2*(M-1)
#define WIN (CHUNK + HALO)    // 1038

__global__ __launch_bounds__(256, 4) void gmp_kernel(const float* __restrict__ x,
                                                     const float* __restrict__ W,
                                                     float* __restrict__ out) {
    __shared__ float2 xs[WIN];   // xc window
    __shared__ float  as[WIN];   // |xc| window
    const int tid   = threadIdx.x;
    const int chunk = blockIdx.x & 15;   // T/CHUNK = 16 chunks per row
    const int b     = blockIdx.x >> 4;
    const int j0    = chunk * CHUNK;

    // Stage window [j0-14, j0+1024) of row b; zero-pad g<0.
    for (int q = tid; q < WIN; q += 256) {
        const int g = j0 - HALO + q;
        float2 v = make_float2(0.f, 0.f);
        if (g >= 0) v = ((const float2*)x)[(size_t)b * T_SZ + g];
        xs[q] = v;
        as[q] = sqrtf(fmaf(v.x, v.x, v.y * v.y));
    }
    __syncthreads();

    // Each thread: outputs j = j0 + 4*tid + {0,1,2,3}.
    const int t4 = 4 * tid;

    // Initial windows in registers (compile-time indices only from here on).
    float a0 = as[t4 + 0], a1 = as[t4 + 1], a2 = as[t4 + 2], a3 = as[t4 + 3];
    float a4 = as[t4 + 4], a5 = as[t4 + 5], a6 = as[t4 + 6], a7 = as[t4 + 7];
    float a8 = as[t4 + 8], a9 = as[t4 + 9], a10 = as[t4 + 10];
    float2 x0 = xs[t4 + 7], x1 = xs[t4 + 8], x2 = xs[t4 + 9], x3 = xs[t4 + 10];

    const float*  __restrict__ arefill = &as[t4 + 11];
    const float2* __restrict__ xrefill = &xs[t4 + 11];

    float ar0 = 0.f, ar1 = 0.f, ar2 = 0.f, ar3 = 0.f;
    float ai0 = 0.f, ai1 = 0.f, ai2 = 0.f, ai3 = 0.f;

#define STEP(W1, W2, W3, A0, A1, A2, A3)                                   \
    {                                                                      \
        const float w1_ = (W1), w2_ = (W2), w3_ = (W3);                    \
        float h;                                                           \
        h = fmaf(A0, w3_, w2_); h = fmaf(A0, h, w1_); c0 = fmaf(A0, h, c0);\
        h = fmaf(A1, w3_, w2_); h = fmaf(A1, h, w1_); c1 = fmaf(A1, h, c1);\
        h = fmaf(A2, w3_, w2_); h = fmaf(A2, h, w1_); c2 = fmaf(A2, h, c2);\
        h = fmaf(A3, w3_, w2_); h = fmaf(A3, h, w1_); c3 = fmaf(A3, h, c3);\
    }

#pragma unroll 1
    for (int i = 0; i < 8; ++i) {
        const float* __restrict__ wp = &W[i * 25];   // uniform -> s_loads

        const float w0 = wp[0];
        float c0 = w0, c1 = w0, c2 = w0, c3 = w0;

        STEP(wp[1],  wp[2],  wp[3],  a0, a1, a2, a3)   // m=0
        STEP(wp[4],  wp[5],  wp[6],  a1, a2, a3, a4)   // m=1
        STEP(wp[7],  wp[8],  wp[9],  a2, a3, a4, a5)   // m=2
        STEP(wp[10], wp[11], wp[12], a3, a4, a5, a6)   // m=3
        STEP(wp[13], wp[14], wp[15], a4, a5, a6, a7)   // m=4
        STEP(wp[16], wp[17], wp[18], a5, a6, a7, a8)   // m=5
        STEP(wp[19], wp[20], wp[21], a6, a7, a8, a9)   // m=6
        STEP(wp[22], wp[23], wp[24], a7, a8, a9, a10)  // m=7

        ar0 = fmaf(x0.x, c0, ar0); ai0 = fmaf(x0.y, c0, ai0);
        ar1 = fmaf(x1.x, c1, ar1); ai1 = fmaf(x1.y, c1, ai1);
        ar2 = fmaf(x2.x, c2, ar2); ai2 = fmaf(x2.y, c2, ai2);
        ar3 = fmaf(x3.x, c3, ar3); ai3 = fmaf(x3.y, c3, ai3);

        if (i < 7) {  // wave-uniform branch (scalar)
            a0 = a1; a1 = a2; a2 = a3; a3 = a4; a4 = a5;
            a5 = a6; a6 = a7; a7 = a8; a8 = a9; a9 = a10;
            a10 = arefill[i];
            x0 = x1; x1 = x2; x2 = x3;
            x3 = xrefill[i];
        }
    }
#undef STEP

    // Four consecutive complex outputs -> two 16B stores.
    float4* op = (float4*)&out[2 * ((size_t)b * T_SZ + j0 + t4)];
    op[0] = make_float4(ar0, ai0, ar1, ai1);
    op[1] = make_float4(ar2, ai2, ar3, ai3);
}

extern "C" void kernel_launch(void* const* d_in, const int* in_sizes, int n_in,
                              void* d_out, int out_size, void* d_ws, size_t ws_size,
                              hipStream_t stream) {
    const float* x = (const float*)d_in[0];
    // d_in[1] is h_0 (unused)
    const float* W = (const float*)d_in[2];
    float* out = (float*)d_out;
    const int grid = B_SZ * (T_SZ / CHUNK);  // 1024 blocks
    gmp_kernel<<<dim3(grid), dim3(256), 0, stream>>>(x, W, out);
}